// Round 1
// baseline (65.928 us; speedup 1.0000x reference)
//
#include <hip/hip_runtime.h>

// Problem: loss = || F^T F - S^T S ||_F^2 / (8192*8192*64*64)
// with F = input.reshape(64, 8192).T, S = target.reshape(64, 8192).T
// (exact rewrite of sum((FF^T)^2 + (SS^T)^2 - 2(FS^T)^2) for c=0, d=2)

#define CH    64
#define KTOT  8192
#define G1    256            // k-slice blocks
#define KPB   (KTOT / G1)    // 32 k per block
#define CHUNK 16
#define NCHUNK (KPB / CHUNK) // 2

// 1 / (8192 * 8192 * 64 * 64) = 2^-38
#define NORMF 3.637978807091713e-12f

__global__ __launch_bounds__(256) void gram_partial(
    const float* __restrict__ in, const float* __restrict__ tg,
    float* __restrict__ ws)
{
    // Transposed LDS tiles: [kk][ch] so fragment reads are contiguous in ch.
    __shared__ __attribute__((aligned(16))) float ts_in[CHUNK][CH];
    __shared__ __attribute__((aligned(16))) float ts_tg[CHUNK][CH];

    const int t   = threadIdx.x;
    const int blk = blockIdx.x;
    const int k0  = blk * KPB;

    // staging indices: thread t loads float4 of row lch at k-offset lko
    const int lch = t >> 2;         // 0..63
    const int lko = (t & 3) << 2;   // 0,4,8,12

    // compute indices: 16x16 thread grid, 4x4 tile each -> full 64x64
    const int ty = t >> 4;          // 0..15
    const int tx = t & 15;          // 0..15
    const int a0 = ty << 2;
    const int b0 = tx << 2;

    float acc[4][4];
#pragma unroll
    for (int i = 0; i < 4; ++i)
#pragma unroll
        for (int j = 0; j < 4; ++j) acc[i][j] = 0.f;

#pragma unroll
    for (int c = 0; c < NCHUNK; ++c) {
        const int kc = k0 + c * CHUNK;
        // global -> LDS (transposed scatter; tiny traffic, 4-way write conflict ok)
        const float4 vi = *(const float4*)(in + lch * KTOT + kc + lko);
        const float4 vt = *(const float4*)(tg + lch * KTOT + kc + lko);
        ts_in[lko + 0][lch] = vi.x; ts_in[lko + 1][lch] = vi.y;
        ts_in[lko + 2][lch] = vi.z; ts_in[lko + 3][lch] = vi.w;
        ts_tg[lko + 0][lch] = vt.x; ts_tg[lko + 1][lch] = vt.y;
        ts_tg[lko + 2][lch] = vt.z; ts_tg[lko + 3][lch] = vt.w;
        __syncthreads();

#pragma unroll
        for (int kk = 0; kk < CHUNK; ++kk) {
            const float4 av = *(const float4*)&ts_in[kk][a0];
            const float4 bv = *(const float4*)&ts_in[kk][b0];
            const float4 cv = *(const float4*)&ts_tg[kk][a0];
            const float4 dv = *(const float4*)&ts_tg[kk][b0];
            const float aa[4] = {av.x, av.y, av.z, av.w};
            const float bb[4] = {bv.x, bv.y, bv.z, bv.w};
            const float cc[4] = {cv.x, cv.y, cv.z, cv.w};
            const float dd[4] = {dv.x, dv.y, dv.z, dv.w};
#pragma unroll
            for (int i = 0; i < 4; ++i)
#pragma unroll
                for (int j = 0; j < 4; ++j) {
                    acc[i][j] = fmaf(aa[i], bb[j], acc[i][j]);
                    acc[i][j] = fmaf(-cc[i], dd[j], acc[i][j]);
                }
        }
        __syncthreads();
    }

    // write 4096-float partial (layout within the 4096 slot is irrelevant
    // to kernel 2 as long as it's consistent across blocks)
    float* p = ws + blk * 4096;
#pragma unroll
    for (int i = 0; i < 4; ++i) {
        float4 v;
        v.x = acc[i][0]; v.y = acc[i][1]; v.z = acc[i][2]; v.w = acc[i][3];
        *(float4*)(p + (a0 + i) * 64 + b0) = v;
    }
}

__global__ __launch_bounds__(256) void reduce_square(
    const float* __restrict__ ws, float* __restrict__ out)
{
    __shared__ float red[4][64];
    const int t  = threadIdx.x;
    const int el = t & 63;                    // entry within block
    const int e  = (blockIdx.x << 6) + el;    // gram entry 0..4095
    const int sl = t >> 6;                    // partial slice 0..3

    float s = 0.f;
    const int p0 = sl * (G1 / 4);
#pragma unroll 8
    for (int p = p0; p < p0 + (G1 / 4); ++p)
        s += ws[p * 4096 + e];
    red[sl][el] = s;
    __syncthreads();

    if (sl == 0) {  // threads 0..63 = wave 0
        float tot = red[0][el] + red[1][el] + red[2][el] + red[3][el];
        float sq  = tot * tot;
#pragma unroll
        for (int off = 32; off > 0; off >>= 1)
            sq += __shfl_down(sq, off);
        if (el == 0) atomicAdd(out, sq * NORMF);
    }
}

extern "C" void kernel_launch(void* const* d_in, const int* in_sizes, int n_in,
                              void* d_out, int out_size, void* d_ws, size_t ws_size,
                              hipStream_t stream)
{
    const float* in = (const float*)d_in[0];
    const float* tg = (const float*)d_in[1];
    float* out = (float*)d_out;
    float* ws  = (float*)d_ws;   // needs G1*4096*4 = 4 MiB

    hipMemsetAsync(out, 0, sizeof(float), stream);
    gram_partial<<<G1, 256, 0, stream>>>(in, tg, ws);
    reduce_square<<<64, 256, 0, stream>>>(ws, out);
}